// Round 8
// baseline (81.594 us; speedup 1.0000x reference)
//
#include <hip/hip_runtime.h>
#include <hip/hip_bf16.h>

// MultiHeadAttention (additive/Bahdanau): B=2, Q=K=256, HIDDEN=1024, 8 heads x 128
// Pipeline (3 kernels):
//  1) prep:      split query/keys -> bf16 hi/lo; W^T*2log2e -> bf16 hi/lo (LDS transpose)
//  2) gemm_mfma: 3-term bf16 MFMA GEMMs -> hq_f[512][1024], hkT[1024][512] (transposed free)
//  3) attn_fused: logits -> softmax -> weights + PV -> ctx.
//     Sharding: wave = (1 q row, 1 k-half of 128), lane = 2 k.
//     Inner math: ONE trans/element: t = exp2(-|a|); tanh = sign(a)*(1 - t*P(t)),
//     P = deg-6 poly approx of 2/(1+t) on [0,1] (max err ~8e-6). Va*tanh = vs - vs*t*P,
//     vs = Va xor signbit(a). (R6 used exp2+rcp = 2 trans -> trans-pipe-bound at ~54us.)
// Requires ws_size >= 16 MB (verified in earlier rounds).

#define TANH_SCALE 2.88539008177792681472f   // 2*log2(e)
#define LOG2E      1.44269504088896340736f

typedef __attribute__((ext_vector_type(8))) short bf16x8_t;   // 8 bf16 = 4 VGPRs
typedef __attribute__((ext_vector_type(4))) float f32x4_t;

__device__ inline ushort bf16_rne(float f) {
  unsigned u = __float_as_uint(f);
  u += 0x7FFFu + ((u >> 16) & 1u);
  return (ushort)(u >> 16);
}
__device__ inline float bf16_to_f(ushort h) { return __uint_as_float((unsigned)h << 16); }
__device__ inline void split1(float v, ushort& hi, ushort& lo) {
  hi = bf16_rne(v);
  lo = bf16_rne(v - bf16_to_f(hi));
}

// ---------------- Kernel 1: prep (split_A + split_WT fused) ----------------
__global__ __launch_bounds__(256) void prep(
    const float* __restrict__ query, const float* __restrict__ keys,
    const float* __restrict__ Wq, const float* __restrict__ Wk,
    ushort* __restrict__ qhi, ushort* __restrict__ qlo,
    ushort* __restrict__ khi, ushort* __restrict__ klo,
    ushort* __restrict__ wqthi, ushort* __restrict__ wqtlo,
    ushort* __restrict__ wkthi, ushort* __restrict__ wktlo)
{
  __shared__ float t[64][65];
  const int bid = blockIdx.x, tid = threadIdx.x;
  if (bid < 1024) {
    const int z = bid >> 9;
    const float* in = z ? keys : query;
    ushort* hi = z ? khi : qhi;
    ushort* lo = z ? klo : qlo;
    const size_t i = ((size_t)(bid & 511) * 256 + tid) * 4;
    float4 v = *(const float4*)(in + i);
    ushort h0, h1, h2, h3, l0, l1, l2, l3;
    split1(v.x, h0, l0); split1(v.y, h1, l1);
    split1(v.z, h2, l2); split1(v.w, h3, l3);
    *(ushort4*)(hi + i) = make_ushort4(h0, h1, h2, h3);
    *(ushort4*)(lo + i) = make_ushort4(l0, l1, l2, l3);
  } else {
    const int idx = bid - 1024;
    const int z = idx >> 8;
    const float* W = z ? Wk : Wq;
    ushort* thi = z ? wkthi : wqthi;
    ushort* tlo = z ? wktlo : wqtlo;
    const int n0 = (idx & 15) * 64, h0 = ((idx >> 4) & 15) * 64;
    const int r = tid >> 4, c = (tid & 15) * 4;
#pragma unroll
    for (int i = 0; i < 4; ++i) {
      const int rr = r + i * 16;
      float4 wv = *(const float4*)(W + (size_t)(h0 + rr) * 1024 + n0 + c);
      t[rr][c + 0] = wv.x; t[rr][c + 1] = wv.y;
      t[rr][c + 2] = wv.z; t[rr][c + 3] = wv.w;
    }
    __syncthreads();
#pragma unroll
    for (int i = 0; i < 4; ++i) {
      const int rr = r + i * 16;   // local n row of output
      ushort h0v, h1v, h2v, h3v, l0v, l1v, l2v, l3v;
      split1(t[c + 0][rr] * TANH_SCALE, h0v, l0v);
      split1(t[c + 1][rr] * TANH_SCALE, h1v, l1v);
      split1(t[c + 2][rr] * TANH_SCALE, h2v, l2v);
      split1(t[c + 3][rr] * TANH_SCALE, h3v, l3v);
      *(ushort4*)(thi + (size_t)(n0 + rr) * 1024 + h0 + c) = make_ushort4(h0v, h1v, h2v, h3v);
      *(ushort4*)(tlo + (size_t)(n0 + rr) * 1024 + h0 + c) = make_ushort4(l0v, l1v, l2v, l3v);
    }
  }
}

// ---------------- Kernel 2: MFMA GEMM, 3-term bf16 split (unchanged) ----------------
__global__ __launch_bounds__(256) void gemm_mfma(
    const ushort* __restrict__ qhi, const ushort* __restrict__ qlo,
    const ushort* __restrict__ khi, const ushort* __restrict__ klo,
    const ushort* __restrict__ wqthi, const ushort* __restrict__ wqtlo,
    const ushort* __restrict__ wkthi, const ushort* __restrict__ wktlo,
    float* __restrict__ hq_f, float* __restrict__ hkT)
{
  const int z = blockIdx.y;
  const int bid = blockIdx.x;
  int m0, n0, ldc;
  const ushort *Ah_g, *Al_g, *Bh_g, *Bl_g;
  float* C;
  if (z == 0) {
    m0 = (bid >> 4) * 64; n0 = (bid & 15) * 64; ldc = 1024;
    Ah_g = qhi; Al_g = qlo; Bh_g = wqthi; Bl_g = wqtlo; C = hq_f;
  } else {
    m0 = (bid >> 3) * 64; n0 = (bid & 7) * 64; ldc = 512;
    Ah_g = wkthi; Al_g = wktlo; Bh_g = khi; Bl_g = klo; C = hkT;
  }

  __shared__ __align__(16) ushort Ah[64 * 40];
  __shared__ __align__(16) ushort Al[64 * 40];
  __shared__ __align__(16) ushort Bh[64 * 40];
  __shared__ __align__(16) ushort Bl[64 * 40];

  const int tid = threadIdx.x;
  const int srow = tid >> 2, skc = (tid & 3) * 8;
  const size_t gA = (size_t)(m0 + srow) * 1024 + skc;
  const size_t gB = (size_t)(n0 + srow) * 1024 + skc;
  const int soff = srow * 40 + skc;

  uint4 rah = *(const uint4*)(Ah_g + gA);
  uint4 ral = *(const uint4*)(Al_g + gA);
  uint4 rbh = *(const uint4*)(Bh_g + gB);
  uint4 rbl = *(const uint4*)(Bl_g + gB);

  const int w = __builtin_amdgcn_readfirstlane(tid >> 6);
  const int lane = tid & 63;
  const int wm = (w >> 1) * 32, wn = (w & 1) * 32;
  const int fr = lane & 15, kg = lane >> 4;
  const int aoff = (wm + fr) * 40 + kg * 8;
  const int boff = (wn + fr) * 40 + kg * 8;

  f32x4_t acc[2][2] = {};

  for (int kk = 0; kk < 1024; kk += 32) {
    __syncthreads();
    *(uint4*)(Ah + soff) = rah;
    *(uint4*)(Al + soff) = ral;
    *(uint4*)(Bh + soff) = rbh;
    *(uint4*)(Bl + soff) = rbl;
    __syncthreads();

    if (kk + 32 < 1024) {
      rah = *(const uint4*)(Ah_g + gA + kk + 32);
      ral = *(const uint4*)(Al_g + gA + kk + 32);
      rbh = *(const uint4*)(Bh_g + gB + kk + 32);
      rbl = *(const uint4*)(Bl_g + gB + kk + 32);
    }

    bf16x8_t ah0 = *(const bf16x8_t*)(Ah + aoff);
    bf16x8_t ah1 = *(const bf16x8_t*)(Ah + aoff + 16 * 40);
    bf16x8_t al0 = *(const bf16x8_t*)(Al + aoff);
    bf16x8_t al1 = *(const bf16x8_t*)(Al + aoff + 16 * 40);
    bf16x8_t bh0 = *(const bf16x8_t*)(Bh + boff);
    bf16x8_t bh1 = *(const bf16x8_t*)(Bh + boff + 16 * 40);
    bf16x8_t bl0 = *(const bf16x8_t*)(Bl + boff);
    bf16x8_t bl1 = *(const bf16x8_t*)(Bl + boff + 16 * 40);

    acc[0][0] = __builtin_amdgcn_mfma_f32_16x16x32_bf16(ah0, bh0, acc[0][0], 0, 0, 0);
    acc[0][1] = __builtin_amdgcn_mfma_f32_16x16x32_bf16(ah0, bh1, acc[0][1], 0, 0, 0);
    acc[1][0] = __builtin_amdgcn_mfma_f32_16x16x32_bf16(ah1, bh0, acc[1][0], 0, 0, 0);
    acc[1][1] = __builtin_amdgcn_mfma_f32_16x16x32_bf16(ah1, bh1, acc[1][1], 0, 0, 0);
    acc[0][0] = __builtin_amdgcn_mfma_f32_16x16x32_bf16(ah0, bl0, acc[0][0], 0, 0, 0);
    acc[0][1] = __builtin_amdgcn_mfma_f32_16x16x32_bf16(ah0, bl1, acc[0][1], 0, 0, 0);
    acc[1][0] = __builtin_amdgcn_mfma_f32_16x16x32_bf16(ah1, bl0, acc[1][0], 0, 0, 0);
    acc[1][1] = __builtin_amdgcn_mfma_f32_16x16x32_bf16(ah1, bl1, acc[1][1], 0, 0, 0);
    acc[0][0] = __builtin_amdgcn_mfma_f32_16x16x32_bf16(al0, bh0, acc[0][0], 0, 0, 0);
    acc[0][1] = __builtin_amdgcn_mfma_f32_16x16x32_bf16(al0, bh1, acc[0][1], 0, 0, 0);
    acc[1][0] = __builtin_amdgcn_mfma_f32_16x16x32_bf16(al1, bh0, acc[1][0], 0, 0, 0);
    acc[1][1] = __builtin_amdgcn_mfma_f32_16x16x32_bf16(al1, bh1, acc[1][1], 0, 0, 0);
  }

#pragma unroll
  for (int fm = 0; fm < 2; ++fm)
#pragma unroll
    for (int fn = 0; fn < 2; ++fn) {
      const int col = n0 + wn + fn * 16 + fr;
#pragma unroll
      for (int j = 0; j < 4; ++j) {
        const int row = m0 + wm + fm * 16 + kg * 4 + j;
        C[(size_t)row * ldc + col] = acc[fm][fn][j];
      }
    }
}

// ---------------- Kernel 3: fused logits + softmax + PV, 2048 blocks ----------------
// block: (b,h) = bid>>7; q rows {2*(bid&127), +1}. Wave w: row r = w>>1, k-half kh = w&1.
// Lane l: k = kh*128 + 2l, 2l+1. Softmax combined across wave pairs via LDS.
// Per element: t = exp2(-|a|) [1 trans]; P(t) ~ 2/(1+t) deg-6; Va*tanh = vs - vs*t*P.
#define TANH_TERM(hqv, ekv, vav, accP, accS)                                   \
  {                                                                            \
    float a_ = (hqv) + (ekv);                                                  \
    float t_ = __builtin_amdgcn_exp2f(-__builtin_fabsf(a_));                   \
    float P_ = fmaf(fmaf(fmaf(fmaf(fmaf(fmaf(0.14773504f, t_, -0.65849088f),  \
               t_, 1.35049944f), t_, -1.8139584f), t_, 1.97255536f),           \
               t_, -1.99841152f), t_, 2.0f);                                   \
    float vs_ = __uint_as_float(__float_as_uint(vav) ^                         \
                                (__float_as_uint(a_) & 0x80000000u));          \
    accS += vs_;                                                               \
    accP = fmaf(vs_ * t_, P_, accP);                                           \
  }

__global__ __launch_bounds__(256) void attn_fused(
    const float* __restrict__ hq_f, const float* __restrict__ hkT,
    const float* __restrict__ Va, const int* __restrict__ mask,
    const float* __restrict__ values,
    float* __restrict__ weights, float* __restrict__ ctx)
{
  __shared__ float red_m[4];
  __shared__ float red_s[4];
  __shared__ __align__(16) float w_lds[2][256];
  __shared__ __align__(16) float pv_part[4][32][4];

  const int tid = threadIdx.x;
  const int lane = tid & 63;
  const int w = __builtin_amdgcn_readfirstlane(tid >> 6);
  const int r = w >> 1, kh = w & 1;
  const int bid = blockIdx.x;
  const int bh = bid >> 7;
  const int b = bh & 1, h = bh >> 1;
  const int q = (bid & 127) * 2 + r;          // global q row (wave-uniform)
  const int k0 = kh * 128 + 2 * lane;         // lane's first k

  // penalties for this lane's 2 k
  const int2 mk = *(const int2*)(mask + b * 256 + k0);
  const float pen0 = 99.0f * (1.0f - (float)mk.x);
  const float pen1 = 99.0f * (1.0f - (float)mk.y);

  const float* ekb = hkT + (size_t)(h * 128) * 512 + b * 256 + k0;   // per-lane, stride 512/d
  const float* hqp = hq_f + (size_t)(b * 256 + q) * 1024 + h * 128;  // wave-uniform
  const float* vap = Va + h * 128;                                   // wave-uniform

  float s0e = 0.f, s0o = 0.f, s1e = 0.f, s1o = 0.f;   // sum of vs
  float p0e = 0.f, p0o = 0.f, p1e = 0.f, p1o = 0.f;   // sum of vs*t*P

  float2 e0 = *(const float2*)(ekb + 0 * 512);
  float2 e1 = *(const float2*)(ekb + 1 * 512);
  float2 e2 = *(const float2*)(ekb + 2 * 512);
  float2 e3 = *(const float2*)(ekb + 3 * 512);
  float4 hq4 = *(const float4*)(hqp);
  float4 va4 = *(const float4*)(vap);

  for (int g = 0; g < 32; ++g) {
    float2 n0v, n1v, n2v, n3v; float4 nhq, nva;
    if (g < 31) {   // prefetch next d-group
      const float* nb = ekb + (size_t)(4 * g + 4) * 512;
      n0v = *(const float2*)(nb + 0 * 512);
      n1v = *(const float2*)(nb + 1 * 512);
      n2v = *(const float2*)(nb + 2 * 512);
      n3v = *(const float2*)(nb + 3 * 512);
      nhq = *(const float4*)(hqp + 4 * g + 4);
      nva = *(const float4*)(vap + 4 * g + 4);
    }
    TANH_TERM(hq4.x, e0.x, va4.x, p0e, s0e);
    TANH_TERM(hq4.x, e0.y, va4.x, p1e, s1e);
    TANH_TERM(hq4.y, e1.x, va4.y, p0o, s0o);
    TANH_TERM(hq4.y, e1.y, va4.y, p1o, s1o);
    TANH_TERM(hq4.z, e2.x, va4.z, p0e, s0e);
    TANH_TERM(hq4.z, e2.y, va4.z, p1e, s1e);
    TANH_TERM(hq4.w, e3.x, va4.w, p0o, s0o);
    TANH_TERM(hq4.w, e3.y, va4.w, p1o, s1o);
    if (g < 31) {
      e0 = n0v; e1 = n1v; e2 = n2v; e3 = n3v;
      hq4 = nhq; va4 = nva;
    }
  }

  const float l0 = (s0e + s0o) - (p0e + p0o) - pen0;
  const float l1 = (s1e + s1o) - (p1e + p1o) - pen1;

  // ---- softmax across the wave pair sharing row r ----
  float mx = fmaxf(l0, l1);
#pragma unroll
  for (int off = 32; off; off >>= 1) mx = fmaxf(mx, __shfl_xor(mx, off, 64));
  if (lane == 0) red_m[w] = mx;
  __syncthreads();
  const float m = fmaxf(mx, red_m[w ^ 1]);

  float p0 = __builtin_amdgcn_exp2f((l0 - m) * LOG2E);
  float p1 = __builtin_amdgcn_exp2f((l1 - m) * LOG2E);
  float s = p0 + p1;
#pragma unroll
  for (int off = 32; off; off >>= 1) s += __shfl_xor(s, off, 64);
  if (lane == 0) red_s[w] = s;
  __syncthreads();
  const float invS = 1.0f / (s + red_s[w ^ 1]);
  p0 *= invS; p1 *= invS;

  float* wp = weights + ((size_t)((b * 8 + h) * 256) + q) * 256 + k0;
  wp[0] = p0; wp[1] = p1;
  w_lds[r][k0] = p0; w_lds[r][k0 + 1] = p1;
  __syncthreads();

  // ---- PV: wave w covers (row r, k in [kh*128 + ks*64, +64)), lane: d4 = lane&31 ----
  const int d4 = lane & 31, ks = lane >> 5;
  const float* vb = values + (size_t)(b * 256 + kh * 128 + ks * 64) * 1024 + h * 128 + d4 * 4;
  const float* wr = &w_lds[r][kh * 128 + ks * 64];
  float4 accE = make_float4(0, 0, 0, 0), accO = make_float4(0, 0, 0, 0);
#pragma unroll 4
  for (int k = 0; k < 64; k += 2) {
    float4 v0 = *(const float4*)&vb[k * 1024];
    float4 v1 = *(const float4*)&vb[(k + 1) * 1024];
    float w0 = wr[k], w1 = wr[k + 1];
    accE.x += w0 * v0.x; accE.y += w0 * v0.y; accE.z += w0 * v0.z; accE.w += w0 * v0.w;
    accO.x += w1 * v1.x; accO.y += w1 * v1.y; accO.z += w1 * v1.z; accO.w += w1 * v1.w;
  }
  float4 a;
  a.x = accE.x + accO.x; a.y = accE.y + accO.y;
  a.z = accE.z + accO.z; a.w = accE.w + accO.w;
  a.x += __shfl_xor(a.x, 32, 64);
  a.y += __shfl_xor(a.y, 32, 64);
  a.z += __shfl_xor(a.z, 32, 64);
  a.w += __shfl_xor(a.w, 32, 64);
  if (lane < 32) *(float4*)&pv_part[w][d4][0] = a;
  __syncthreads();

  if (tid < 64) {
    const int rr = tid >> 5, dd = tid & 31;
    float4 pa = *(const float4*)&pv_part[2 * rr][dd][0];
    float4 pb = *(const float4*)&pv_part[2 * rr + 1][dd][0];
    float4 o;
    o.x = pa.x + pb.x; o.y = pa.y + pb.y; o.z = pa.z + pb.z; o.w = pa.w + pb.w;
    const int qg = (bid & 127) * 2 + rr;
    *(float4*)&ctx[(size_t)(b * 256 + qg) * 1024 + h * 128 + dd * 4] = o;
  }
}

extern "C" void kernel_launch(void* const* d_in, const int* in_sizes, int n_in,
                              void* d_out, int out_size, void* d_ws, size_t ws_size,
                              hipStream_t stream) {
  const float* query  = (const float*)d_in[0];
  const float* keys   = (const float*)d_in[1];
  const float* values = (const float*)d_in[2];
  const int*   mask   = (const int*)d_in[3];
  const float* Wq     = (const float*)d_in[4];
  const float* Wk     = (const float*)d_in[5];
  const float* Va     = (const float*)d_in[6];

  float* ctx     = (float*)d_out;            // [2,256,1024]
  float* weights = ctx + 524288;             // [2,8,256,256]

  // ws layout (16 MB total):
  ushort* qhi   = (ushort*)d_ws;             // 512K elems each
  ushort* qlo   = qhi + 524288;
  ushort* khi   = qlo + 524288;
  ushort* klo   = khi + 524288;
  ushort* wqthi = klo + 524288;              // 1M elems each
  ushort* wqtlo = wqthi + 1048576;
  ushort* wkthi = wqtlo + 1048576;
  ushort* wktlo = wkthi + 1048576;
  float*  hq_f  = (float*)(wktlo + 1048576); // [512][1024]
  float*  hkT   = hq_f + 524288;             // [1024][512]

  prep<<<dim3(1536), 256, 0, stream>>>(query, keys, Wq, Wk,
                                       qhi, qlo, khi, klo,
                                       wqthi, wqtlo, wkthi, wktlo);
  gemm_mfma<<<dim3(128, 2), 256, 0, stream>>>(qhi, qlo, khi, klo,
                                              wqthi, wqtlo, wkthi, wktlo, hq_f, hkT);
  attn_fused<<<dim3(2048), 256, 0, stream>>>(hq_f, hkT, Va, mask, values, weights, ctx);
}

// Round 9
// 75.487 us; speedup vs baseline: 1.0809x; 1.0809x over previous
//
#include <hip/hip_runtime.h>
#include <hip/hip_bf16.h>

// MultiHeadAttention (additive/Bahdanau): B=2, Q=K=256, HIDDEN=1024, 8 heads x 128
// Pipeline (3 kernels):
//  1) prep:      split query/keys -> bf16 hi/lo; W^T*2log2e -> bf16 hi/lo (LDS transpose)
//  2) gemm_mfma: 3-term bf16 MFMA GEMMs -> hq_f[512][1024], hkT[1024][512] (transposed free)
//  3) attn_fused: block = (b,h,8-q-tile); wave = 64 k (1 k/lane). hk chunk (16 d) held in
//     REGISTERS across all 8 q rows (8x load reuse, ~1400-cyc prefetch window); hq/Va are
//     wave-uniform scalar loads. logits -> in-block softmax -> weights + PV -> ctx.
// tanh(x) = 1 - 2/(e^{2x}+1); a = 2log2e*x -> e^{2x} = 2^a. Saturates correctly at +-inf.
// Requires ws_size >= 16 MB (verified in earlier rounds).

#define TANH_SCALE 2.88539008177792681472f   // 2*log2(e)
#define LOG2E      1.44269504088896340736f

typedef __attribute__((ext_vector_type(8))) short bf16x8_t;   // 8 bf16 = 4 VGPRs
typedef __attribute__((ext_vector_type(4))) float f32x4_t;

__device__ inline ushort bf16_rne(float f) {
  unsigned u = __float_as_uint(f);
  u += 0x7FFFu + ((u >> 16) & 1u);
  return (ushort)(u >> 16);
}
__device__ inline float bf16_to_f(ushort h) { return __uint_as_float((unsigned)h << 16); }
__device__ inline void split1(float v, ushort& hi, ushort& lo) {
  hi = bf16_rne(v);
  lo = bf16_rne(v - bf16_to_f(hi));
}

// ---------------- Kernel 1: prep (unchanged) ----------------
__global__ __launch_bounds__(256) void prep(
    const float* __restrict__ query, const float* __restrict__ keys,
    const float* __restrict__ Wq, const float* __restrict__ Wk,
    ushort* __restrict__ qhi, ushort* __restrict__ qlo,
    ushort* __restrict__ khi, ushort* __restrict__ klo,
    ushort* __restrict__ wqthi, ushort* __restrict__ wqtlo,
    ushort* __restrict__ wkthi, ushort* __restrict__ wktlo)
{
  __shared__ float t[64][65];
  const int bid = blockIdx.x, tid = threadIdx.x;
  if (bid < 1024) {
    const int z = bid >> 9;
    const float* in = z ? keys : query;
    ushort* hi = z ? khi : qhi;
    ushort* lo = z ? klo : qlo;
    const size_t i = ((size_t)(bid & 511) * 256 + tid) * 4;
    float4 v = *(const float4*)(in + i);
    ushort h0, h1, h2, h3, l0, l1, l2, l3;
    split1(v.x, h0, l0); split1(v.y, h1, l1);
    split1(v.z, h2, l2); split1(v.w, h3, l3);
    *(ushort4*)(hi + i) = make_ushort4(h0, h1, h2, h3);
    *(ushort4*)(lo + i) = make_ushort4(l0, l1, l2, l3);
  } else {
    const int idx = bid - 1024;
    const int z = idx >> 8;
    const float* W = z ? Wk : Wq;
    ushort* thi = z ? wkthi : wqthi;
    ushort* tlo = z ? wktlo : wqtlo;
    const int n0 = (idx & 15) * 64, h0 = ((idx >> 4) & 15) * 64;
    const int r = tid >> 4, c = (tid & 15) * 4;
#pragma unroll
    for (int i = 0; i < 4; ++i) {
      const int rr = r + i * 16;
      float4 wv = *(const float4*)(W + (size_t)(h0 + rr) * 1024 + n0 + c);
      t[rr][c + 0] = wv.x; t[rr][c + 1] = wv.y;
      t[rr][c + 2] = wv.z; t[rr][c + 3] = wv.w;
    }
    __syncthreads();
#pragma unroll
    for (int i = 0; i < 4; ++i) {
      const int rr = r + i * 16;
      ushort h0v, h1v, h2v, h3v, l0v, l1v, l2v, l3v;
      split1(t[c + 0][rr] * TANH_SCALE, h0v, l0v);
      split1(t[c + 1][rr] * TANH_SCALE, h1v, l1v);
      split1(t[c + 2][rr] * TANH_SCALE, h2v, l2v);
      split1(t[c + 3][rr] * TANH_SCALE, h3v, l3v);
      *(ushort4*)(thi + (size_t)(n0 + rr) * 1024 + h0 + c) = make_ushort4(h0v, h1v, h2v, h3v);
      *(ushort4*)(tlo + (size_t)(n0 + rr) * 1024 + h0 + c) = make_ushort4(l0v, l1v, l2v, l3v);
    }
  }
}

// ---------------- Kernel 2: MFMA GEMM, 3-term bf16 split (unchanged) ----------------
__global__ __launch_bounds__(256) void gemm_mfma(
    const ushort* __restrict__ qhi, const ushort* __restrict__ qlo,
    const ushort* __restrict__ khi, const ushort* __restrict__ klo,
    const ushort* __restrict__ wqthi, const ushort* __restrict__ wqtlo,
    const ushort* __restrict__ wkthi, const ushort* __restrict__ wktlo,
    float* __restrict__ hq_f, float* __restrict__ hkT)
{
  const int z = blockIdx.y;
  const int bid = blockIdx.x;
  int m0, n0, ldc;
  const ushort *Ah_g, *Al_g, *Bh_g, *Bl_g;
  float* C;
  if (z == 0) {
    m0 = (bid >> 4) * 64; n0 = (bid & 15) * 64; ldc = 1024;
    Ah_g = qhi; Al_g = qlo; Bh_g = wqthi; Bl_g = wqtlo; C = hq_f;
  } else {
    m0 = (bid >> 3) * 64; n0 = (bid & 7) * 64; ldc = 512;
    Ah_g = wkthi; Al_g = wktlo; Bh_g = khi; Bl_g = klo; C = hkT;
  }

  __shared__ __align__(16) ushort Ah[64 * 40];
  __shared__ __align__(16) ushort Al[64 * 40];
  __shared__ __align__(16) ushort Bh[64 * 40];
  __shared__ __align__(16) ushort Bl[64 * 40];

  const int tid = threadIdx.x;
  const int srow = tid >> 2, skc = (tid & 3) * 8;
  const size_t gA = (size_t)(m0 + srow) * 1024 + skc;
  const size_t gB = (size_t)(n0 + srow) * 1024 + skc;
  const int soff = srow * 40 + skc;

  uint4 rah = *(const uint4*)(Ah_g + gA);
  uint4 ral = *(const uint4*)(Al_g + gA);
  uint4 rbh = *(const uint4*)(Bh_g + gB);
  uint4 rbl = *(const uint4*)(Bl_g + gB);

  const int w = __builtin_amdgcn_readfirstlane(tid >> 6);
  const int lane = tid & 63;
  const int wm = (w >> 1) * 32, wn = (w & 1) * 32;
  const int fr = lane & 15, kg = lane >> 4;
  const int aoff = (wm + fr) * 40 + kg * 8;
  const int boff = (wn + fr) * 40 + kg * 8;

  f32x4_t acc[2][2] = {};

  for (int kk = 0; kk < 1024; kk += 32) {
    __syncthreads();
    *(uint4*)(Ah + soff) = rah;
    *(uint4*)(Al + soff) = ral;
    *(uint4*)(Bh + soff) = rbh;
    *(uint4*)(Bl + soff) = rbl;
    __syncthreads();

    if (kk + 32 < 1024) {
      rah = *(const uint4*)(Ah_g + gA + kk + 32);
      ral = *(const uint4*)(Al_g + gA + kk + 32);
      rbh = *(const uint4*)(Bh_g + gB + kk + 32);
      rbl = *(const uint4*)(Bl_g + gB + kk + 32);
    }

    bf16x8_t ah0 = *(const bf16x8_t*)(Ah + aoff);
    bf16x8_t ah1 = *(const bf16x8_t*)(Ah + aoff + 16 * 40);
    bf16x8_t al0 = *(const bf16x8_t*)(Al + aoff);
    bf16x8_t al1 = *(const bf16x8_t*)(Al + aoff + 16 * 40);
    bf16x8_t bh0 = *(const bf16x8_t*)(Bh + boff);
    bf16x8_t bh1 = *(const bf16x8_t*)(Bh + boff + 16 * 40);
    bf16x8_t bl0 = *(const bf16x8_t*)(Bl + boff);
    bf16x8_t bl1 = *(const bf16x8_t*)(Bl + boff + 16 * 40);

    acc[0][0] = __builtin_amdgcn_mfma_f32_16x16x32_bf16(ah0, bh0, acc[0][0], 0, 0, 0);
    acc[0][1] = __builtin_amdgcn_mfma_f32_16x16x32_bf16(ah0, bh1, acc[0][1], 0, 0, 0);
    acc[1][0] = __builtin_amdgcn_mfma_f32_16x16x32_bf16(ah1, bh0, acc[1][0], 0, 0, 0);
    acc[1][1] = __builtin_amdgcn_mfma_f32_16x16x32_bf16(ah1, bh1, acc[1][1], 0, 0, 0);
    acc[0][0] = __builtin_amdgcn_mfma_f32_16x16x32_bf16(ah0, bl0, acc[0][0], 0, 0, 0);
    acc[0][1] = __builtin_amdgcn_mfma_f32_16x16x32_bf16(ah0, bl1, acc[0][1], 0, 0, 0);
    acc[1][0] = __builtin_amdgcn_mfma_f32_16x16x32_bf16(ah1, bl0, acc[1][0], 0, 0, 0);
    acc[1][1] = __builtin_amdgcn_mfma_f32_16x16x32_bf16(ah1, bl1, acc[1][1], 0, 0, 0);
    acc[0][0] = __builtin_amdgcn_mfma_f32_16x16x32_bf16(al0, bh0, acc[0][0], 0, 0, 0);
    acc[0][1] = __builtin_amdgcn_mfma_f32_16x16x32_bf16(al0, bh1, acc[0][1], 0, 0, 0);
    acc[1][0] = __builtin_amdgcn_mfma_f32_16x16x32_bf16(al1, bh0, acc[1][0], 0, 0, 0);
    acc[1][1] = __builtin_amdgcn_mfma_f32_16x16x32_bf16(al1, bh1, acc[1][1], 0, 0, 0);
  }

#pragma unroll
  for (int fm = 0; fm < 2; ++fm)
#pragma unroll
    for (int fn = 0; fn < 2; ++fn) {
      const int col = n0 + wn + fn * 16 + fr;
#pragma unroll
      for (int j = 0; j < 4; ++j) {
        const int row = m0 + wm + fm * 16 + kg * 4 + j;
        C[(size_t)row * ldc + col] = acc[fm][fn][j];
      }
    }
}

// ---------------- Kernel 3: fused attn, q-tiled registers ----------------
// grid 512: block = (b,h) = bid>>5, q-tile = (bid&31)*8. Wave w: k = w*64+lane.
// hk chunk (16 d) in regs, reused across 8 q. hq/Va wave-uniform (scalar). R6 math (5 instr/elem).
#define TT(hqv, hkv, vav, accq)                                     \
  {                                                                 \
    float a_ = (hqv) + (hkv);                                       \
    float e_ = __builtin_amdgcn_exp2f(a_);                          \
    accq += (vav) * __builtin_amdgcn_rcpf(e_ + 1.0f);               \
  }

__global__ __launch_bounds__(256) void attn_fused(
    const float* __restrict__ hq_f, const float* __restrict__ hkT,
    const float* __restrict__ Va, const int* __restrict__ mask,
    const float* __restrict__ values,
    float* __restrict__ weights, float* __restrict__ ctx)
{
  __shared__ float red_m[4][8];
  __shared__ float red_s[4][8];
  __shared__ __align__(16) float P_lds[8][256];

  const int tid = threadIdx.x;
  const int lane = tid & 63;
  const int w = __builtin_amdgcn_readfirstlane(tid >> 6);
  const int bid = blockIdx.x;
  const int bh = bid >> 5;
  const int b = bh & 1, h = bh >> 1;
  const int qt = (bid & 31) * 8;
  const int k = w * 64 + lane;

  const float pen = 99.0f * (1.0f - (float)mask[b * 256 + k]);

  float ssum = Va[h * 128 + lane] + Va[h * 128 + 64 + lane];
#pragma unroll
  for (int off = 32; off; off >>= 1) ssum += __shfl_xor(ssum, off, 64);

  const float* hkp = hkT + (size_t)(h * 128) * 512 + b * 256 + k;     // + d*512
  const float* hqb = hq_f + (size_t)(b * 256 + qt) * 1024 + h * 128;  // + q*1024 + d
  const float* vap = Va + h * 128;

  float acc[8] = {0.f, 0.f, 0.f, 0.f, 0.f, 0.f, 0.f, 0.f};

  float hkc[16], vac[16];
#pragma unroll
  for (int j = 0; j < 16; ++j) hkc[j] = hkp[(size_t)j * 512];
#pragma unroll
  for (int j = 0; j < 16; ++j) vac[j] = vap[j];

  for (int ch = 0; ch < 8; ++ch) {
    const int d0 = ch * 16;
    float hkn[16], van[16];
    if (ch < 7) {   // prefetch next chunk; consumed after the full 8-q pass (~1400 cyc window)
#pragma unroll
      for (int j = 0; j < 16; ++j) hkn[j] = hkp[(size_t)(d0 + 16 + j) * 512];
#pragma unroll
      for (int j = 0; j < 16; ++j) van[j] = vap[d0 + 16 + j];
    }
#pragma unroll
    for (int q = 0; q < 8; ++q) {
      const float* hqq = hqb + (size_t)q * 1024 + d0;   // wave-uniform
      float4 a0 = *(const float4*)(hqq + 0);
      float4 a1 = *(const float4*)(hqq + 4);
      float4 a2 = *(const float4*)(hqq + 8);
      float4 a3 = *(const float4*)(hqq + 12);
      TT(a0.x, hkc[0],  vac[0],  acc[q]);
      TT(a0.y, hkc[1],  vac[1],  acc[q]);
      TT(a0.z, hkc[2],  vac[2],  acc[q]);
      TT(a0.w, hkc[3],  vac[3],  acc[q]);
      TT(a1.x, hkc[4],  vac[4],  acc[q]);
      TT(a1.y, hkc[5],  vac[5],  acc[q]);
      TT(a1.z, hkc[6],  vac[6],  acc[q]);
      TT(a1.w, hkc[7],  vac[7],  acc[q]);
      TT(a2.x, hkc[8],  vac[8],  acc[q]);
      TT(a2.y, hkc[9],  vac[9],  acc[q]);
      TT(a2.z, hkc[10], vac[10], acc[q]);
      TT(a2.w, hkc[11], vac[11], acc[q]);
      TT(a3.x, hkc[12], vac[12], acc[q]);
      TT(a3.y, hkc[13], vac[13], acc[q]);
      TT(a3.z, hkc[14], vac[14], acc[q]);
      TT(a3.w, hkc[15], vac[15], acc[q]);
    }
    if (ch < 7) {
#pragma unroll
      for (int j = 0; j < 16; ++j) { hkc[j] = hkn[j]; vac[j] = van[j]; }
    }
  }

  // logits
  float l[8], p[8];
#pragma unroll
  for (int q = 0; q < 8; ++q) l[q] = ssum - 2.0f * acc[q] - pen;

  // row max: wave-reduce then cross-wave via LDS
#pragma unroll
  for (int q = 0; q < 8; ++q) {
    float m = l[q];
#pragma unroll
    for (int off = 32; off; off >>= 1) m = fmaxf(m, __shfl_xor(m, off, 64));
    if (lane == 0) red_m[w][q] = m;
  }
  __syncthreads();
#pragma unroll
  for (int q = 0; q < 8; ++q) {
    float m = fmaxf(fmaxf(red_m[0][q], red_m[1][q]), fmaxf(red_m[2][q], red_m[3][q]));
    p[q] = __builtin_amdgcn_exp2f((l[q] - m) * LOG2E);
  }
#pragma unroll
  for (int q = 0; q < 8; ++q) {
    float s = p[q];
#pragma unroll
    for (int off = 32; off; off >>= 1) s += __shfl_xor(s, off, 64);
    if (lane == 0) red_s[w][q] = s;
  }
  __syncthreads();
#pragma unroll
  for (int q = 0; q < 8; ++q) {
    const float s = (red_s[0][q] + red_s[1][q]) + (red_s[2][q] + red_s[3][q]);
    const float pq = p[q] / s;
    weights[((size_t)((b * 8 + h) * 256) + qt + q) * 256 + k] = pq;
    P_lds[q][k] = pq;
  }
  __syncthreads();

  // PV: wave w -> q rows {2w, 2w+1}; lane: d4 = lane&31, ks = lane>>5 (k-half).
  const int d4 = lane & 31, ks = lane >> 5;
  const int q0 = w * 2, q1 = q0 + 1;
  const float* vb = values + (size_t)(b * 256 + ks * 128) * 1024 + h * 128 + d4 * 4;
  float4 A0 = make_float4(0, 0, 0, 0), A1 = make_float4(0, 0, 0, 0);
#pragma unroll 2
  for (int k4 = 0; k4 < 32; ++k4) {
    float4 p0v = *(const float4*)&P_lds[q0][ks * 128 + k4 * 4];
    float4 p1v = *(const float4*)&P_lds[q1][ks * 128 + k4 * 4];
#pragma unroll
    for (int j = 0; j < 4; ++j) {
      float4 v = *(const float4*)(vb + (size_t)(k4 * 4 + j) * 1024);
      const float pj0 = (j == 0) ? p0v.x : (j == 1) ? p0v.y : (j == 2) ? p0v.z : p0v.w;
      const float pj1 = (j == 0) ? p1v.x : (j == 1) ? p1v.y : (j == 2) ? p1v.z : p1v.w;
      A0.x += pj0 * v.x; A0.y += pj0 * v.y; A0.z += pj0 * v.z; A0.w += pj0 * v.w;
      A1.x += pj1 * v.x; A1.y += pj1 * v.y; A1.z += pj1 * v.z; A1.w += pj1 * v.w;
    }
  }
  A0.x += __shfl_xor(A0.x, 32, 64); A0.y += __shfl_xor(A0.y, 32, 64);
  A0.z += __shfl_xor(A0.z, 32, 64); A0.w += __shfl_xor(A0.w, 32, 64);
  A1.x += __shfl_xor(A1.x, 32, 64); A1.y += __shfl_xor(A1.y, 32, 64);
  A1.z += __shfl_xor(A1.z, 32, 64); A1.w += __shfl_xor(A1.w, 32, 64);
  if (lane < 32) {
    *(float4*)&ctx[(size_t)(b * 256 + qt + q0) * 1024 + h * 128 + d4 * 4] = A0;
    *(float4*)&ctx[(size_t)(b * 256 + qt + q1) * 1024 + h * 128 + d4 * 4] = A1;
  }
}

extern "C" void kernel_launch(void* const* d_in, const int* in_sizes, int n_in,
                              void* d_out, int out_size, void* d_ws, size_t ws_size,
                              hipStream_t stream) {
  const float* query  = (const float*)d_in[0];
  const float* keys   = (const float*)d_in[1];
  const float* values = (const float*)d_in[2];
  const int*   mask   = (const int*)d_in[3];
  const float* Wq     = (const float*)d_in[4];
  const float* Wk     = (const float*)d_in[5];
  const float* Va     = (const float*)d_in[6];

  float* ctx     = (float*)d_out;            // [2,256,1024]
  float* weights = ctx + 524288;             // [2,8,256,256]

  ushort* qhi   = (ushort*)d_ws;
  ushort* qlo   = qhi + 524288;
  ushort* khi   = qlo + 524288;
  ushort* klo   = khi + 524288;
  ushort* wqthi = klo + 524288;
  ushort* wqtlo = wqthi + 1048576;
  ushort* wkthi = wqtlo + 1048576;
  ushort* wktlo = wkthi + 1048576;
  float*  hq_f  = (float*)(wktlo + 1048576); // [512][1024]
  float*  hkT   = hq_f + 524288;             // [1024][512]

  prep<<<dim3(1536), 256, 0, stream>>>(query, keys, Wq, Wk,
                                       qhi, qlo, khi, klo,
                                       wqthi, wqtlo, wkthi, wktlo);
  gemm_mfma<<<dim3(128, 2), 256, 0, stream>>>(qhi, qlo, khi, klo,
                                              wqthi, wqtlo, wkthi, wktlo, hq_f, hkT);
  attn_fused<<<dim3(512), 256, 0, stream>>>(hq_f, hkT, Va, mask, values, weights, ctx);
}